// Round 7
// baseline (439.333 us; speedup 1.0000x reference)
//
#include <hip/hip_runtime.h>

#define TSEQ 256
#define FIN  32
#define HID  64

typedef _Float16 f16x8 __attribute__((ext_vector_type(8)));
typedef float    f32x4 __attribute__((ext_vector_type(4)));

__device__ __forceinline__ float wsum(float v) {
    #pragma unroll
    for (int off = 32; off > 0; off >>= 1) v += __shfl_xor(v, off, 64);
    return v;
}

// DPP row_ror:8 — dest lane i gets source lane (i+8) mod 16 within its row.
__device__ __forceinline__ float ror8(float v) {
    return __int_as_float(__builtin_amdgcn_update_dpp(
        0, __float_as_int(v), 0x128, 0xF, 0xF, true));
}

// Merged-rcp LSTM cell: 5 exp + 3 rcp.
__device__ __forceinline__ float lstm_cell(const f32x4 g, float& c) {
    float ei = __expf(-g[0]);
    float ef = __expf(-g[1]);
    float yg = __expf(2.0f * g[2]);
    float eo = __expf(-g[3]);
    float sf = __builtin_amdgcn_rcpf(1.0f + ef);
    float ig = (yg - 1.0f) * __builtin_amdgcn_rcpf((1.0f + ei) * (yg + 1.0f));
    c = fmaf(sf, c, ig);
    float cc = fminf(fmaxf(c, -15.0f), 15.0f);
    float yc = __expf(2.0f * cc);
    return (yc - 1.0f) * __builtin_amdgcn_rcpf((1.0f + eo) * (yc + 1.0f));
}

// R7: 512 blocks x 512 threads (8 waves), 8 batch rows per block -> TWO
// independent blocks per CU (their barriers interleave, filling the ~40%
// lockstep idle of the 1-block/CU R6). Wave w owns gate tiles {w, w+8}
// (n' = 4d+type permutation) for both layers; the two half-valid (8-row)
// C-fragments are packed into one full-wave decode via DPP row_ror:8:
// lanes lm<8 decode tile w (batch=lm, d=w*4+q), lanes lm>=8 decode tile
// w+8 (batch=lm-8, d=(w+8)*4+q). Skew pipeline (one barrier per interval)
// and all dataflow/parity logic carried from R6 (proven).
__global__ __launch_bounds__(512, 4)
void lstm_fused(const float* __restrict__ x,
                const float* __restrict__ w_ih0, const float* __restrict__ w_hh0,
                const float* __restrict__ b_ih0, const float* __restrict__ b_hh0,
                const float* __restrict__ w_ih1, const float* __restrict__ w_hh1,
                const float* __restrict__ b_ih1, const float* __restrict__ b_hh1,
                const float* __restrict__ ln_g, const float* __restrict__ ln_b,
                const float* __restrict__ w1, const float* __restrict__ b1,
                const float* __restrict__ w2, const float* __restrict__ b2,
                float* __restrict__ out)
{
    __shared__ __align__(16) _Float16 X[2][16][32];   // rows 8-15 = zero pad
    __shared__ __align__(16) _Float16 H0[2][16][72];  // rows 8-15 = zero pad
    __shared__ __align__(16) _Float16 H1[2][16][72];
    __shared__ __align__(16) float HF[8][68];         // final h1 (fp32) for head
    __shared__ __align__(16) float LNB[8][64];        // per-wave layernorm row

    const int tid  = threadIdx.x;
    const int wave = tid >> 6;    // 0..7
    const int lane = tid & 63;
    const int q    = lane >> 4;
    const int lm   = lane & 15;
    const int q8   = q * 8;
    const int b0   = blockIdx.x * 8;

    // packed decode mapping: lanes lm<8 -> tile A (T=wave), lm>=8 -> tile B (T=wave+8)
    const int blm = lm & 7;                                   // batch row decoded
    const int pd  = (lm < 8) ? (wave * 4 + q) : ((wave + 8) * 4 + q);  // d decoded

    // ---- weights as A-fragments for tiles A and B: lane holds A[m=lm][k=q8+j] ----
    f16x8 w0fA[3], w0fB[3], w1fA[4], w1fB[4];
    f32x4 bias0A, bias0B, bias1A, bias1B;
    #pragma unroll
    for (int tb = 0; tb < 2; ++tb) {
        const int T    = wave + 8 * tb;
        const int np   = T * 16 + lm;
        const int drow = np >> 2;
        const int ty   = np & 3;
        const int row  = ty * 64 + drow;
        const int dq   = T * 4 + q;
        f16x8* w0f = tb ? w0fB : w0fA;
        f16x8* w1f = tb ? w1fB : w1fA;
        const float* p0 = w_ih0 + row * FIN + q8;
        const float* p1 = w_hh0 + row * HID + q8;
        const float* p2 = w_hh0 + row * HID + 32 + q8;
        const float* p3 = w_ih1 + row * HID + q8;
        const float* p4 = w_ih1 + row * HID + 32 + q8;
        const float* p5 = w_hh1 + row * HID + q8;
        const float* p6 = w_hh1 + row * HID + 32 + q8;
        #pragma unroll
        for (int j = 0; j < 8; ++j) {
            w0f[0][j] = (_Float16)p0[j];
            w0f[1][j] = (_Float16)p1[j];
            w0f[2][j] = (_Float16)p2[j];
            w1f[0][j] = (_Float16)p3[j];
            w1f[1][j] = (_Float16)p4[j];
            w1f[2][j] = (_Float16)p5[j];
            w1f[3][j] = (_Float16)p6[j];
        }
        f32x4 bb0, bb1;
        #pragma unroll
        for (int r = 0; r < 4; ++r) {
            bb0[r] = b_ih0[r * 64 + dq] + b_hh0[r * 64 + dq];
            bb1[r] = b_ih1[r * 64 + dq] + b_hh1[r * 64 + dq];
        }
        if (tb) { bias0B = bb0; bias1B = bb1; } else { bias0A = bb0; bias1A = bb1; }
    }

    // ---- zero all state (incl. pad rows; pads are never rewritten) ----
    for (int i = tid; i < 2 * 16 * 72; i += 512) {
        ((_Float16*)H0)[i] = (_Float16)0.0f;
        ((_Float16*)H1)[i] = (_Float16)0.0f;
    }
    for (int i = tid; i < 2 * 16 * 32; i += 512) ((_Float16*)X)[i] = (_Float16)0.0f;
    __syncthreads();

    // ---- x staging: lanes 0-31 of wave w stage batch row w ----
    const bool xlane = lane < 32;
    const int  xcol  = lane & 31;
    const float* xbase = x + (size_t)(b0 + wave) * TSEQ * FIN + xcol;
    if (xlane) X[0][wave][xcol] = (_Float16)xbase[0];
    float xw = xbase[FIN];   // x(1)

    float c0 = 0.0f, c1 = 0.0f;   // packed cell states for (blm, pd)
    __syncthreads();

// Interval i (parity P=i&1): phase A computes h0(i): reads X[P], H0[P^1],
// writes H0[P]. Phase B computes h1(i-1): reads H0[P^1], H1[P], writes
// H1[P^1]. x: store X[P^1] <- xw (=x(i+1)), load xw <- x(XI).
#define PACK(dst, a0v, a1v)                                                     \
    {                                                                           \
        _Pragma("unroll")                                                       \
        for (int r = 0; r < 4; ++r) {                                           \
            float rv = ror8(a1v[r]);                                            \
            dst[r] = (lm < 8) ? a0v[r] : rv;                                    \
        }                                                                       \
    }

#define INTERVAL(P, DO_A, DO_B, DO_XSTORE, DO_XLOAD, XI)                        \
    {                                                                           \
        float xnew = 0.0f;                                                      \
        if (DO_XLOAD) xnew = xbase[(size_t)(XI) * FIN];                         \
        f16x8 rh0a = *reinterpret_cast<const f16x8*>(&H0[(P) ^ 1][lm][q8]);     \
        f16x8 rh0b = *reinterpret_cast<const f16x8*>(&H0[(P) ^ 1][lm][32 + q8]);\
        if (DO_A) {                                                             \
            f16x8 rx = *reinterpret_cast<const f16x8*>(&X[P][lm][q8]);          \
            f32x4 a0 = bias0A, a1 = bias0B;                                     \
            a0 = __builtin_amdgcn_mfma_f32_16x16x32_f16(w0fA[0], rx,   a0, 0, 0, 0); \
            a1 = __builtin_amdgcn_mfma_f32_16x16x32_f16(w0fB[0], rx,   a1, 0, 0, 0); \
            a0 = __builtin_amdgcn_mfma_f32_16x16x32_f16(w0fA[1], rh0a, a0, 0, 0, 0); \
            a1 = __builtin_amdgcn_mfma_f32_16x16x32_f16(w0fB[1], rh0a, a1, 0, 0, 0); \
            a0 = __builtin_amdgcn_mfma_f32_16x16x32_f16(w0fA[2], rh0b, a0, 0, 0, 0); \
            a1 = __builtin_amdgcn_mfma_f32_16x16x32_f16(w0fB[2], rh0b, a1, 0, 0, 0); \
            f32x4 pa; PACK(pa, a0, a1)                                          \
            float hA = lstm_cell(pa, c0);                                       \
            H0[P][blm][pd] = (_Float16)hA;                                      \
        }                                                                       \
        if (DO_B) {                                                             \
            f16x8 rh1a = *reinterpret_cast<const f16x8*>(&H1[P][lm][q8]);       \
            f16x8 rh1b = *reinterpret_cast<const f16x8*>(&H1[P][lm][32 + q8]);  \
            f32x4 a0 = bias1A, a1 = bias1B;                                     \
            a0 = __builtin_amdgcn_mfma_f32_16x16x32_f16(w1fA[0], rh0a, a0, 0, 0, 0); \
            a1 = __builtin_amdgcn_mfma_f32_16x16x32_f16(w1fB[0], rh0a, a1, 0, 0, 0); \
            a0 = __builtin_amdgcn_mfma_f32_16x16x32_f16(w1fA[1], rh0b, a0, 0, 0, 0); \
            a1 = __builtin_amdgcn_mfma_f32_16x16x32_f16(w1fB[1], rh0b, a1, 0, 0, 0); \
            a0 = __builtin_amdgcn_mfma_f32_16x16x32_f16(w1fA[2], rh1a, a0, 0, 0, 0); \
            a1 = __builtin_amdgcn_mfma_f32_16x16x32_f16(w1fB[2], rh1a, a1, 0, 0, 0); \
            a0 = __builtin_amdgcn_mfma_f32_16x16x32_f16(w1fA[3], rh1b, a0, 0, 0, 0); \
            a1 = __builtin_amdgcn_mfma_f32_16x16x32_f16(w1fB[3], rh1b, a1, 0, 0, 0); \
            f32x4 pb; PACK(pb, a0, a1)                                          \
            float hB = lstm_cell(pb, c1);                                       \
            H1[(P) ^ 1][blm][pd] = (_Float16)hB;                                \
            lastB = hB;                                                         \
        }                                                                       \
        if (DO_XSTORE && xlane) X[(P) ^ 1][wave][xcol] = (_Float16)xw;          \
        xw = xnew;                                                              \
        __syncthreads();                                                        \
    }

    float lastB = 0.0f;

    // peel i = 0 (P=0): A only; store x(1), load x(2)
    INTERVAL(0, true, false, true, true, 2)

    // main: i = 1..254 as 127 (odd,even) pairs, fully active
    #pragma unroll 1
    for (int ii = 0; ii < 127; ++ii) {
        const int i1  = 2 * ii + 1;
        const int xiA = (i1 + 2 > 255) ? 255 : i1 + 2;
        const int xiB = (i1 + 3 > 255) ? 255 : i1 + 3;
        INTERVAL(1, true, true, true, true, xiA)
        INTERVAL(0, true, true, true, true, xiB)
    }

    // peel i = 255 (P=1): A+B, no x staging
    INTERVAL(1, true, true, false, false, 0)
    // peel i = 256 (P=0): B only -> h1(255)
    INTERVAL(0, false, true, false, false, 0)
    HF[blm][pd] = lastB;
    __syncthreads();

#undef INTERVAL
#undef PACK

    // ================= Head: LayerNorm + MLP (wave w -> batch row w) =========
    const float lngv = ln_g[lane], lnbv = ln_b[lane];
    const float b1v = b1[lane], w2v = w2[lane];
    const float* w1row = w1 + lane * 64;
    {
        float v  = HF[wave][lane];
        float mu = wsum(v) * (1.0f / 64.0f);
        float dv = v - mu;
        float var = wsum(dv * dv) * (1.0f / 64.0f);
        float ln = dv * rsqrtf(var + 1e-5f) * lngv + lnbv;
        LNB[wave][lane] = ln;   // wave-private buffer
        float s = b1v;
        #pragma unroll
        for (int dd = 0; dd < 64; ++dd)
            s = fmaf(LNB[wave][dd], w1row[dd], s);
        s = fmaxf(s, 0.0f);
        float y = wsum(s * w2v);
        if (lane == 0) out[b0 + wave] = y + b2[0];
    }
}

extern "C" void kernel_launch(void* const* d_in, const int* in_sizes, int n_in,
                              void* d_out, int out_size, void* d_ws, size_t ws_size,
                              hipStream_t stream) {
    const float* x     = (const float*)d_in[0];
    const float* w_ih0 = (const float*)d_in[1];
    const float* w_hh0 = (const float*)d_in[2];
    const float* b_ih0 = (const float*)d_in[3];
    const float* b_hh0 = (const float*)d_in[4];
    const float* w_ih1 = (const float*)d_in[5];
    const float* w_hh1 = (const float*)d_in[6];
    const float* b_ih1 = (const float*)d_in[7];
    const float* b_hh1 = (const float*)d_in[8];
    const float* ln_g  = (const float*)d_in[9];
    const float* ln_b  = (const float*)d_in[10];
    const float* w1    = (const float*)d_in[11];
    const float* b1    = (const float*)d_in[12];
    const float* w2    = (const float*)d_in[13];
    const float* b2    = (const float*)d_in[14];
    lstm_fused<<<dim3(512), dim3(512), 0, stream>>>(
        x, w_ih0, w_hh0, b_ih0, b_hh0,
        w_ih1, w_hh1, b_ih1, b_hh1,
        ln_g, ln_b, w1, b1, w2, b2, (float*)d_out);
}